// Round 13
// baseline (429.723 us; speedup 1.0000x reference)
//
#include <hip/hip_runtime.h>
#include <hip/hip_bf16.h>

typedef short bf16x8 __attribute__((ext_vector_type(8)));
typedef float f32x4 __attribute__((ext_vector_type(4)));

#define LOG2E 1.4426950408889634f
#define QKV_E ((size_t)24*4096*64)

__device__ __forceinline__ float bfu2f(unsigned short u) {
  unsigned v = ((unsigned)u) << 16;
  return __builtin_bit_cast(float, v);
}
__device__ __forceinline__ unsigned short f2bfu(float f) {
  unsigned u = __builtin_bit_cast(unsigned, f);
  u += 0x7fffu + ((u >> 16) & 1u);
  return (unsigned short)(u >> 16);
}
__device__ __forceinline__ unsigned packbf2(float lo, float hi) {
  return (unsigned)f2bfu(lo) | ((unsigned)f2bfu(hi) << 16);
}
__device__ __forceinline__ float gelu_f(float v) {
  float a = fabsf(v) * 0.70710678118654752f;
  float t = 1.0f / (1.0f + 0.3275911f * a);
  float poly = ((((1.061405429f * t - 1.453152027f) * t + 1.421413741f) * t
                 - 0.284496736f) * t + 0.254829592f) * t;
  float erfa = 1.0f - poly * __expf(-a * a);
  float erfv = v >= 0.0f ? erfa : -erfa;
  return 0.5f * v * (1.0f + erfv);
}
__device__ __forceinline__ void gl_lds16(const ushort* g, ushort* l) {
  __builtin_amdgcn_global_load_lds(
      (const __attribute__((address_space(1))) unsigned int*)(const void*)g,
      (__attribute__((address_space(3))) unsigned int*)(void*)l, 16, 0, 0);
}

// ---------------- RMSNorm ----------------
__global__ __launch_bounds__(256) void rmsnorm_k(const float* __restrict__ x,
    const float* __restrict__ w, ushort* __restrict__ xn) {
  int row = blockIdx.x, t = threadIdx.x;
  const float* xr = x + (size_t)row * 768;
  float v0 = xr[t], v1 = xr[t + 256], v2 = xr[t + 512];
  float ss = v0 * v0 + v1 * v1 + v2 * v2;
#pragma unroll
  for (int m = 32; m >= 1; m >>= 1) ss += __shfl_xor(ss, m, 64);
  __shared__ float part[4];
  if ((t & 63) == 0) part[t >> 6] = ss;
  __syncthreads();
  float tot = part[0] + part[1] + part[2] + part[3];
  float rr = rsqrtf(tot * (1.0f / 768.0f) + 1e-6f);
  ushort* xo = xn + (size_t)row * 768;
  xo[t]       = f2bfu(v0 * rr * w[t]);
  xo[t + 256] = f2bfu(v1 * rr * w[t + 256]);
  xo[t + 512] = f2bfu(v2 * rr * w[t + 512]);
}

// ------------- transpose + fp32->bf16 -------------
__global__ __launch_bounds__(256) void tcvt_k(const float* __restrict__ in,
    ushort* __restrict__ out, int R, int C) {
  __shared__ float tile[32][33];
  int c0 = blockIdx.x * 32, r0 = blockIdx.y * 32;
  int t = threadIdx.x;
  int j = t & 31, i0 = t >> 5;
#pragma unroll
  for (int i = i0; i < 32; i += 8) tile[i][j] = in[(size_t)(r0 + i) * C + c0 + j];
  __syncthreads();
#pragma unroll
  for (int i = i0; i < 32; i += 8) out[(size_t)(c0 + i) * R + r0 + j] = f2bfu(tile[j][i]);
}

// ======== GEMM1: 128x128, m97-style single-buffer, 5 blocks/CU ============
__global__ __launch_bounds__(256, 5) void gemm1_k(const ushort* __restrict__ A,
    const ushort* __restrict__ Bt, const float* __restrict__ bias,
    const float* __restrict__ sn, const float* __restrict__ cs,
    ushort* __restrict__ qbuf, ushort* __restrict__ kbuf,
    ushort* __restrict__ vt, ushort* __restrict__ comb) {
  __shared__ __align__(16) ushort lds[2][128 * 64];   // 32 KB: [A|B]
  const int t = threadIdx.x, lane = t & 63, w = t >> 6;
  const int wr = w >> 1, wc = w & 1;
  int bid = blockIdx.x;                       // 2688 = 8 * 336
  int xcd = bid & 7, local = bid >> 3;
  int grp = local / 48, r6 = local % 48;
  int bx = grp * 6 + r6 % 6;
  int by = xcd * 8 + r6 / 6;
  const int mBase = by * 128, nBase = bx * 128;

  size_t gA[4], gB[4];
  int ldst[4];
#pragma unroll
  for (int j = 0; j < 4; ++j) {
    int row = w * 32 + j * 8 + (lane >> 3);
    int gc = ((lane & 7) ^ (lane >> 3)) * 8;
    gA[j] = (size_t)(mBase + row) * 768 + gc;
    gB[j] = (size_t)(nBase + row) * 768 + gc;
    ldst[j] = (w * 32 + j * 8) * 64;
  }

  f32x4 acc[4][4];
  f32x4 z = {0.f, 0.f, 0.f, 0.f};
#pragma unroll
  for (int m = 0; m < 4; ++m)
#pragma unroll
    for (int nn = 0; nn < 4; ++nn) acc[m][nn] = z;

#pragma unroll 1
  for (int kt = 0; kt < 12; ++kt) {
    const int k0 = kt * 64;
    __syncthreads();
#pragma unroll
    for (int j = 0; j < 4; ++j) {
      gl_lds16(A + gA[j] + k0, &lds[0][0] + ldst[j]);
      gl_lds16(Bt + gB[j] + k0, &lds[1][0] + ldst[j]);
    }
    __syncthreads();
#pragma unroll
    for (int kk = 0; kk < 2; ++kk) {
      bf16x8 af[4], bff[4];
#pragma unroll
      for (int m = 0; m < 4; ++m) {
        int row = wr * 64 + m * 16 + (lane & 15);
        int slot = (kk * 4 + (lane >> 4)) ^ (lane & 7);
        af[m] = *(const bf16x8*)(&lds[0][0] + row * 64 + slot * 8);
      }
#pragma unroll
      for (int nn = 0; nn < 4; ++nn) {
        int row = wc * 64 + nn * 16 + (lane & 15);
        int slot = (kk * 4 + (lane >> 4)) ^ (lane & 7);
        bff[nn] = *(const bf16x8*)(&lds[1][0] + row * 64 + slot * 8);
      }
#pragma unroll
      for (int m = 0; m < 4; ++m)
#pragma unroll
        for (int nn = 0; nn < 4; ++nn)
          acc[m][nn] = __builtin_amdgcn_mfma_f32_16x16x32_bf16(bff[nn], af[m], acc[m][nn], 0, 0, 0);
    }
  }

  const bool isff = (nBase >= 2304);
  const int region = nBase / 768;
#pragma unroll
  for (int m = 0; m < 4; ++m) {
    int row = mBase + wr * 64 + m * 16 + (lane & 15);
    int b = row >> 12, s = row & 4095;
#pragma unroll
    for (int nn = 0; nn < 4; ++nn) {
      int col = nBase + wc * 64 + nn * 16 + ((lane >> 4) << 2);
      f32x4 v = acc[m][nn] + *(const f32x4*)(bias + col);
      if (isff) {
        ushort4 o;
        o.x = f2bfu(gelu_f(v[0]));
        o.y = f2bfu(gelu_f(v[1]));
        o.z = f2bfu(gelu_f(v[2]));
        o.w = f2bfu(gelu_f(v[3]));
        *(ushort4*)(comb + (size_t)row * 3840 + (col - 1536)) = o;
      } else {
        int rem = col - region * 768;
        int h = rem >> 6, d0 = rem & 63;
        if (region == 2) {
          int l = s & 127;
          int pnn = l >> 4, pg = (l >> 2) & 3, pr = l & 3;
          int sp = (s & ~127) | (((pnn >> 1) * 4 + pg) * 8 + (pnn & 1) * 4 + pr);
          size_t vb = (size_t)((b * 12 + h) * 64 + d0) * 4096 + sp;
          vt[vb]          = f2bfu(v[0]);
          vt[vb + 4096]   = f2bfu(v[1]);
          vt[vb + 2*4096] = f2bfu(v[2]);
          vt[vb + 3*4096] = f2bfu(v[3]);
        } else {
          f32x4 sv = *(const f32x4*)(sn + (s << 6) + d0);
          f32x4 cv = *(const f32x4*)(cs + (s << 6) + d0);
          float o0 = v[0] * cv[0] - v[1] * sv[0];
          float o1 = v[1] * cv[0] + v[0] * sv[0];
          float o2 = v[2] * cv[2] - v[3] * sv[2];
          float o3 = v[3] * cv[2] + v[2] * sv[2];
          ushort4 o;
          if (region == 0) {
            o.x = f2bfu(o0 * 0.125f); o.y = f2bfu(o1 * 0.125f);
            o.z = f2bfu(o2 * 0.125f); o.w = f2bfu(o3 * 0.125f);
            *(ushort4*)(qbuf + ((size_t)((b * 12 + h) * 4096 + s)) * 64 + d0) = o;
          } else {
            o.x = f2bfu(o0); o.y = f2bfu(o1); o.z = f2bfu(o2); o.w = f2bfu(o3);
            *(ushort4*)(kbuf + ((size_t)((b * 12 + h) * 4096 + s)) * 64 + d0) = o;
          }
        }
      }
    }
  }
}

// ======== GEMM2: in-block split-K=2, two m97 cores + staged LDS reduce ====
__global__ __launch_bounds__(512, 2) void gemm2_k(const ushort* __restrict__ A,
    const ushort* __restrict__ Bt, const float* __restrict__ bias,
    float* __restrict__ out) {
  __shared__ __align__(16) ushort lds[2][2][128 * 64];  // [grp][A/B] 64KB
  const int t = threadIdx.x;
  const int grp = t >> 8, tl = t & 255;
  const int lane = tl & 63, w4 = tl >> 6;
  const int wr = w4 >> 1, wc = w4 & 1;
  int bid = blockIdx.x;                     // 384 = 8 * 48
  int xcd = bid & 7, local = bid >> 3;
  int g = local / 4, r4 = local % 4;
  int bx = (g % 3) * 2 + (r4 & 1);
  int by = xcd * 8 + (g / 3) * 2 + (r4 >> 1);
  const int mBase = by * 128, nBase = bx * 128;
  const int kOff = grp * 1920;

  size_t gA[4], gB[4];
  int ldst[4];
#pragma unroll
  for (int j = 0; j < 4; ++j) {
    int row = w4 * 32 + j * 8 + (lane >> 3);
    int gc = ((lane & 7) ^ (lane >> 3)) * 8;
    gA[j] = (size_t)(mBase + row) * 3840 + kOff + gc;
    gB[j] = (size_t)(nBase + row) * 3840 + kOff + gc;
    ldst[j] = (w4 * 32 + j * 8) * 64;
  }

  f32x4 acc[4][4];
  f32x4 z = {0.f, 0.f, 0.f, 0.f};
#pragma unroll
  for (int m = 0; m < 4; ++m)
#pragma unroll
    for (int nn = 0; nn < 4; ++nn) acc[m][nn] = z;

#pragma unroll 1
  for (int kt = 0; kt < 30; ++kt) {
    const int k0 = kt * 64;
    __syncthreads();
#pragma unroll
    for (int j = 0; j < 4; ++j) {
      gl_lds16(A + gA[j] + k0, &lds[grp][0][0] + ldst[j]);
      gl_lds16(Bt + gB[j] + k0, &lds[grp][1][0] + ldst[j]);
    }
    __syncthreads();
#pragma unroll
    for (int kk = 0; kk < 2; ++kk) {
      bf16x8 af[4], bff[4];
#pragma unroll
      for (int m = 0; m < 4; ++m) {
        int row = wr * 64 + m * 16 + (lane & 15);
        int slot = (kk * 4 + (lane >> 4)) ^ (lane & 7);
        af[m] = *(const bf16x8*)(&lds[grp][0][0] + row * 64 + slot * 8);
      }
#pragma unroll
      for (int nn = 0; nn < 4; ++nn) {
        int row = wc * 64 + nn * 16 + (lane & 15);
        int slot = (kk * 4 + (lane >> 4)) ^ (lane & 7);
        bff[nn] = *(const bf16x8*)(&lds[grp][1][0] + row * 64 + slot * 8);
      }
#pragma unroll
      for (int m = 0; m < 4; ++m)
#pragma unroll
        for (int nn = 0; nn < 4; ++nn)
          acc[m][nn] = __builtin_amdgcn_mfma_f32_16x16x32_bf16(bff[nn], af[m], acc[m][nn], 0, 0, 0);
    }
  }

  f32x4* sc = (f32x4*)&lds[0][0][0];
#pragma unroll
  for (int h = 0; h < 2; ++h) {
    __syncthreads();
    if (grp == 1) {
#pragma unroll
      for (int m = 0; m < 2; ++m)
#pragma unroll
        for (int nn = 0; nn < 4; ++nn)
          sc[(size_t)tl * 8 + m * 4 + nn] = acc[2 * h + m][nn];
    }
    __syncthreads();
    if (grp == 0) {
#pragma unroll
      for (int m = 0; m < 2; ++m) {
        int row = mBase + wr * 64 + (2 * h + m) * 16 + (lane & 15);
#pragma unroll
        for (int nn = 0; nn < 4; ++nn) {
          int col = nBase + wc * 64 + nn * 16 + ((lane >> 4) << 2);
          f32x4 v = acc[2 * h + m][nn] + sc[(size_t)tl * 8 + m * 4 + nn]
                  + *(const f32x4*)(bias + col);
          *(f32x4*)(out + (size_t)row * 768 + col) = v;
        }
      }
    }
  }
}

// ======== windowed attention: single-buffer m97-style, 3-4 blocks/CU ======
// swapped QK^T, P in-register, V pi-permuted; 32KB LDS.
__global__ __launch_bounds__(256, 4) void attn_k(const ushort* __restrict__ qb,
    const ushort* __restrict__ kb, const ushort* __restrict__ vt,
    ushort* __restrict__ comb) {
  __shared__ __align__(16) ushort KS[128 * 64];
  __shared__ __align__(16) ushort VS[64 * 128];
  int bid = blockIdx.x;                      // 768 = 8 * 96
  int nb = (bid & 7) * 96 + (bid >> 3);
  int qt = nb & 31, bh = nb >> 5;
  const int t = threadIdx.x, lane = t & 63, w = t >> 6;
  const int g = lane >> 4, q15 = lane & 15;
  const int qlo = qt * 128;
  const size_t base = (size_t)bh * 4096 * 64;

  size_t kSrc[4], vSrc[4];
  int dstOff[4];
#pragma unroll
  for (int j = 0; j < 4; ++j) {
    int ck = (w * 4 + j) * 64 + lane;
    int key = ck >> 3, sl = ck & 7;
    kSrc[j] = (size_t)key * 64 + ((sl ^ (key & 7)) << 3);
    int dd = ck >> 4, s16 = ck & 15;
    vSrc[j] = (size_t)dd * 4096 + ((s16 ^ (dd & 15)) << 3);
    dstOff[j] = (w * 4 + j) * 512;
  }

  bf16x8 qa[2][2];
#pragma unroll
  for (int m = 0; m < 2; ++m)
#pragma unroll
    for (int kk = 0; kk < 2; ++kk) {
      int row = qlo + w * 32 + m * 16 + q15;
      qa[m][kk] = *(const bf16x8*)(qb + base + (size_t)row * 64 + kk * 32 + g * 8);
    }

  f32x4 z = {0.f, 0.f, 0.f, 0.f};
  f32x4 o[2][4];
#pragma unroll
  for (int m = 0; m < 2; ++m)
#pragma unroll
    for (int df = 0; df < 4; ++df) o[m][df] = z;
  float m_run[2] = {-1e30f, -1e30f}, l_run[2] = {0.f, 0.f};

  const int t0 = qt >= 4 ? qt - 4 : 0;
  const int qrow0 = qlo + w * 32 + q15;
#pragma unroll 1
  for (int kt = t0; kt <= qt; ++kt) {
    const int k0 = kt * 128;
    __syncthreads();   // prior tile's LDS reads done
#pragma unroll
    for (int j = 0; j < 4; ++j) {
      gl_lds16(kb + base + (size_t)k0 * 64 + kSrc[j], &KS[0] + dstOff[j]);
      gl_lds16(vt + base + k0 + vSrc[j], &VS[0] + dstOff[j]);
    }
    __syncthreads();   // staged data landed
    // QK^T (swapped)
    f32x4 s[2][8];
#pragma unroll
    for (int m = 0; m < 2; ++m)
#pragma unroll
      for (int nn = 0; nn < 8; ++nn) s[m][nn] = z;
#pragma unroll
    for (int kk = 0; kk < 2; ++kk) {
      bf16x8 kf[8];
#pragma unroll
      for (int nn = 0; nn < 8; ++nn) {
        int row = nn * 16 + q15;
        int slot = (kk * 4 + g) ^ (q15 & 7);
        kf[nn] = *(const bf16x8*)(&KS[0] + row * 64 + slot * 8);
      }
#pragma unroll
      for (int m = 0; m < 2; ++m)
#pragma unroll
        for (int nn = 0; nn < 8; ++nn)
          s[m][nn] = __builtin_amdgcn_mfma_f32_16x16x32_bf16(kf[nn], qa[m][kk], s[m][nn], 0, 0, 0);
    }
    if (kt == qt) {
#pragma unroll
      for (int m = 0; m < 2; ++m) {
        int ql = qrow0 + m * 16 - k0;
#pragma unroll
        for (int nn = 0; nn < 8; ++nn)
#pragma unroll
          for (int r = 0; r < 4; ++r)
            if (nn * 16 + g * 4 + r > ql) s[m][nn][r] = -3e38f;
      }
    } else if (kt == qt - 4) {
#pragma unroll
      for (int m = 0; m < 2; ++m) {
        int ql = qrow0 + m * 16 - k0;
#pragma unroll
        for (int nn = 0; nn < 8; ++nn)
#pragma unroll
          for (int r = 0; r < 4; ++r)
            if (ql - (nn * 16 + g * 4 + r) >= 512) s[m][nn][r] = -3e38f;
      }
    }
    float mx[2];
    bool need = false;
#pragma unroll
    for (int m = 0; m < 2; ++m) {
      float v = s[m][0][0];
#pragma unroll
      for (int nn = 0; nn < 8; ++nn)
#pragma unroll
        for (int r = 0; r < 4; ++r) v = fmaxf(v, s[m][nn][r]);
      v = fmaxf(v, __shfl_xor(v, 16, 64));
      v = fmaxf(v, __shfl_xor(v, 32, 64));
      mx[m] = v;
      need |= (v > m_run[m] + 8.f);
    }
    if (__any(need)) {
#pragma unroll
      for (int m = 0; m < 2; ++m) {
        float mn = fmaxf(m_run[m], mx[m]);
        float sc = exp2f((m_run[m] - mn) * LOG2E);
        m_run[m] = mn;
        l_run[m] *= sc;
#pragma unroll
        for (int df = 0; df < 4; ++df) o[m][df] *= sc;
      }
    }
#pragma unroll
    for (int m = 0; m < 2; ++m) {
      float mr = m_run[m];
      float ls = 0.f;
#pragma unroll
      for (int nn = 0; nn < 8; ++nn)
#pragma unroll
        for (int r = 0; r < 4; ++r) {
          float p = exp2f((s[m][nn][r] - mr) * LOG2E);
          s[m][nn][r] = p;
          ls += p;
        }
      ls += __shfl_xor(ls, 16, 64);
      ls += __shfl_xor(ls, 32, 64);
      l_run[m] += ls;
    }
#pragma unroll
    for (int kk2 = 0; kk2 < 4; ++kk2) {
      bf16x8 pa[2];
#pragma unroll
      for (int m = 0; m < 2; ++m) {
        int4 pi4;
        pi4.x = (int)packbf2(s[m][2*kk2][0],   s[m][2*kk2][1]);
        pi4.y = (int)packbf2(s[m][2*kk2][2],   s[m][2*kk2][3]);
        pi4.z = (int)packbf2(s[m][2*kk2+1][0], s[m][2*kk2+1][1]);
        pi4.w = (int)packbf2(s[m][2*kk2+1][2], s[m][2*kk2+1][3]);
        pa[m] = __builtin_bit_cast(bf16x8, pi4);
      }
#pragma unroll
      for (int df = 0; df < 4; ++df) {
        int row = df * 16 + q15;
        int slot = (kk2 * 4 + g) ^ q15;
        bf16x8 vf = *(const bf16x8*)(&VS[0] + row * 128 + slot * 8);
#pragma unroll
        for (int m = 0; m < 2; ++m)
          o[m][df] = __builtin_amdgcn_mfma_f32_16x16x32_bf16(vf, pa[m], o[m][df], 0, 0, 0);
      }
    }
  }

  int b = bh / 12, h = bh % 12;
#pragma unroll
  for (int m = 0; m < 2; ++m) {
    float inv = 1.0f / l_run[m];
    int row = qrow0 + m * 16;
#pragma unroll
    for (int df = 0; df < 4; ++df) {
      ushort4 ov;
      ov.x = f2bfu(o[m][df][0] * inv);
      ov.y = f2bfu(o[m][df][1] * inv);
      ov.z = f2bfu(o[m][df][2] * inv);
      ov.w = f2bfu(o[m][df][3] * inv);
      *(ushort4*)(comb + (size_t)(b * 4096 + row) * 3840 + h * 64 + df * 16 + g * 4) = ov;
    }
  }
}

extern "C" void kernel_launch(void* const* d_in, const int* in_sizes, int n_in,
                              void* d_out, int out_size, void* d_ws, size_t ws_size,
                              hipStream_t stream) {
  (void)in_sizes; (void)n_in; (void)out_size; (void)ws_size;
  const float* x      = (const float*)d_in[0];
  const float* sin_t  = (const float*)d_in[1];
  const float* cos_t  = (const float*)d_in[2];
  const float* w_norm = (const float*)d_in[3];
  const float* W_in   = (const float*)d_in[4];
  const float* b_in   = (const float*)d_in[5];
  const float* W_out  = (const float*)d_in[6];
  const float* b_out  = (const float*)d_in[7];
  float* out = (float*)d_out;

  const size_t XN_E  = (size_t)8192 * 768;
  ushort* xn      = (ushort*)d_ws;
  ushort* qbuf    = xn + XN_E;
  ushort* kbuf    = qbuf + QKV_E;
  ushort* vt      = kbuf + QKV_E;
  ushort* w_in_t  = vt + QKV_E;
  ushort* w_out_t = w_in_t + (size_t)5376 * 768;
  ushort* comb    = w_out_t + (size_t)768 * 3840;

  rmsnorm_k<<<dim3(8192), dim3(256), 0, stream>>>(x, w_norm, xn);
  tcvt_k<<<dim3(5376 / 32, 768 / 32), dim3(256), 0, stream>>>(W_in, w_in_t, 768, 5376);
  tcvt_k<<<dim3(768 / 32, 3840 / 32), dim3(256), 0, stream>>>(W_out, w_out_t, 3840, 768);
  gemm1_k<<<dim3(2688), dim3(256), 0, stream>>>(xn, w_in_t, b_in, sin_t, cos_t,
                                                qbuf, kbuf, vt, comb);
  attn_k<<<dim3(768), dim3(256), 0, stream>>>(qbuf, kbuf, vt, comb);
  gemm2_k<<<dim3(384), dim3(512), 0, stream>>>(comb, w_out_t, b_out, out);
}

// Round 14
// 224.591 us; speedup vs baseline: 1.9134x; 1.9134x over previous
//
#include <hip/hip_runtime.h>
#include <hip/hip_bf16.h>

typedef short bf16x8 __attribute__((ext_vector_type(8)));
typedef float f32x4 __attribute__((ext_vector_type(4)));

#define LOG2E 1.4426950408889634f
#define QKV_E ((size_t)24*4096*64)

__device__ __forceinline__ float bfu2f(unsigned short u) {
  unsigned v = ((unsigned)u) << 16;
  return __builtin_bit_cast(float, v);
}
__device__ __forceinline__ unsigned short f2bfu(float f) {
  unsigned u = __builtin_bit_cast(unsigned, f);
  u += 0x7fffu + ((u >> 16) & 1u);
  return (unsigned short)(u >> 16);
}
__device__ __forceinline__ unsigned packbf2(float lo, float hi) {
  return (unsigned)f2bfu(lo) | ((unsigned)f2bfu(hi) << 16);
}
__device__ __forceinline__ float gelu_f(float v) {
  float a = fabsf(v) * 0.70710678118654752f;
  float t = 1.0f / (1.0f + 0.3275911f * a);
  float poly = ((((1.061405429f * t - 1.453152027f) * t + 1.421413741f) * t
                 - 0.284496736f) * t + 0.254829592f) * t;
  float erfa = 1.0f - poly * __expf(-a * a);
  float erfv = v >= 0.0f ? erfa : -erfa;
  return 0.5f * v * (1.0f + erfv);
}
__device__ __forceinline__ void gl_lds16(const ushort* g, ushort* l) {
  __builtin_amdgcn_global_load_lds(
      (const __attribute__((address_space(1))) unsigned int*)(const void*)g,
      (__attribute__((address_space(3))) unsigned int*)(void*)l, 16, 0, 0);
}
#define WAIT_VM8  asm volatile("s_waitcnt vmcnt(8)" ::: "memory")
#define WAIT_VM0  asm volatile("s_waitcnt vmcnt(0)" ::: "memory")
#define WAIT_LGKM asm volatile("s_waitcnt lgkmcnt(0)" ::: "memory")
#define BAR       __builtin_amdgcn_s_barrier()

// ---------------- RMSNorm ----------------
__global__ __launch_bounds__(256) void rmsnorm_k(const float* __restrict__ x,
    const float* __restrict__ w, ushort* __restrict__ xn) {
  int row = blockIdx.x, t = threadIdx.x;
  const float* xr = x + (size_t)row * 768;
  float v0 = xr[t], v1 = xr[t + 256], v2 = xr[t + 512];
  float ss = v0 * v0 + v1 * v1 + v2 * v2;
#pragma unroll
  for (int m = 32; m >= 1; m >>= 1) ss += __shfl_xor(ss, m, 64);
  __shared__ float part[4];
  if ((t & 63) == 0) part[t >> 6] = ss;
  __syncthreads();
  float tot = part[0] + part[1] + part[2] + part[3];
  float rr = rsqrtf(tot * (1.0f / 768.0f) + 1e-6f);
  ushort* xo = xn + (size_t)row * 768;
  xo[t]       = f2bfu(v0 * rr * w[t]);
  xo[t + 256] = f2bfu(v1 * rr * w[t + 256]);
  xo[t + 512] = f2bfu(v2 * rr * w[t + 512]);
}

// ------------- transpose + fp32->bf16 -------------
__global__ __launch_bounds__(256) void tcvt_k(const float* __restrict__ in,
    ushort* __restrict__ out, int R, int C) {
  __shared__ float tile[32][33];
  int c0 = blockIdx.x * 32, r0 = blockIdx.y * 32;
  int t = threadIdx.x;
  int j = t & 31, i0 = t >> 5;
#pragma unroll
  for (int i = i0; i < 32; i += 8) tile[i][j] = in[(size_t)(r0 + i) * C + c0 + j];
  __syncthreads();
#pragma unroll
  for (int i = i0; i < 32; i += 8) out[(size_t)(c0 + i) * R + r0 + j] = f2bfu(tile[j][i]);
}

// ======== GEMM1: 128x128, m97-style single-buffer, 4 blocks/CU ============
__global__ __launch_bounds__(256, 4) void gemm1_k(const ushort* __restrict__ A,
    const ushort* __restrict__ Bt, const float* __restrict__ bias,
    const float* __restrict__ sn, const float* __restrict__ cs,
    ushort* __restrict__ qbuf, ushort* __restrict__ kbuf,
    ushort* __restrict__ vt, ushort* __restrict__ comb) {
  __shared__ __align__(16) ushort lds[2][128 * 64];   // 32 KB: [A|B]
  const int t = threadIdx.x, lane = t & 63, w = t >> 6;
  const int wr = w >> 1, wc = w & 1;
  int bid = blockIdx.x;                       // 2688 = 8 * 336
  int xcd = bid & 7, local = bid >> 3;
  int grp = local / 48, r6 = local % 48;
  int bx = grp * 6 + r6 % 6;
  int by = xcd * 8 + r6 / 6;
  const int mBase = by * 128, nBase = bx * 128;

  size_t gA[4], gB[4];
  int ldst[4];
#pragma unroll
  for (int j = 0; j < 4; ++j) {
    int row = w * 32 + j * 8 + (lane >> 3);
    int gc = ((lane & 7) ^ (lane >> 3)) * 8;
    gA[j] = (size_t)(mBase + row) * 768 + gc;
    gB[j] = (size_t)(nBase + row) * 768 + gc;
    ldst[j] = (w * 32 + j * 8) * 64;
  }

  f32x4 acc[4][4];
  f32x4 z = {0.f, 0.f, 0.f, 0.f};
#pragma unroll
  for (int m = 0; m < 4; ++m)
#pragma unroll
    for (int nn = 0; nn < 4; ++nn) acc[m][nn] = z;

#pragma unroll 1
  for (int kt = 0; kt < 12; ++kt) {
    const int k0 = kt * 64;
    __syncthreads();
#pragma unroll
    for (int j = 0; j < 4; ++j) {
      gl_lds16(A + gA[j] + k0, &lds[0][0] + ldst[j]);
      gl_lds16(Bt + gB[j] + k0, &lds[1][0] + ldst[j]);
    }
    __syncthreads();
#pragma unroll
    for (int kk = 0; kk < 2; ++kk) {
      bf16x8 af[4], bff[4];
#pragma unroll
      for (int m = 0; m < 4; ++m) {
        int row = wr * 64 + m * 16 + (lane & 15);
        int slot = (kk * 4 + (lane >> 4)) ^ (lane & 7);
        af[m] = *(const bf16x8*)(&lds[0][0] + row * 64 + slot * 8);
      }
#pragma unroll
      for (int nn = 0; nn < 4; ++nn) {
        int row = wc * 64 + nn * 16 + (lane & 15);
        int slot = (kk * 4 + (lane >> 4)) ^ (lane & 7);
        bff[nn] = *(const bf16x8*)(&lds[1][0] + row * 64 + slot * 8);
      }
#pragma unroll
      for (int m = 0; m < 4; ++m)
#pragma unroll
        for (int nn = 0; nn < 4; ++nn)
          acc[m][nn] = __builtin_amdgcn_mfma_f32_16x16x32_bf16(bff[nn], af[m], acc[m][nn], 0, 0, 0);
    }
  }

  const bool isff = (nBase >= 2304);
  const int region = nBase / 768;
#pragma unroll
  for (int m = 0; m < 4; ++m) {
    int row = mBase + wr * 64 + m * 16 + (lane & 15);
    int b = row >> 12, s = row & 4095;
#pragma unroll
    for (int nn = 0; nn < 4; ++nn) {
      int col = nBase + wc * 64 + nn * 16 + ((lane >> 4) << 2);
      f32x4 v = acc[m][nn] + *(const f32x4*)(bias + col);
      if (isff) {
        ushort4 o;
        o.x = f2bfu(gelu_f(v[0]));
        o.y = f2bfu(gelu_f(v[1]));
        o.z = f2bfu(gelu_f(v[2]));
        o.w = f2bfu(gelu_f(v[3]));
        *(ushort4*)(comb + (size_t)row * 3840 + (col - 1536)) = o;
      } else {
        int rem = col - region * 768;
        int h = rem >> 6, d0 = rem & 63;
        if (region == 2) {
          int l = s & 127;
          int pnn = l >> 4, pg = (l >> 2) & 3, pr = l & 3;
          int sp = (s & ~127) | (((pnn >> 1) * 4 + pg) * 8 + (pnn & 1) * 4 + pr);
          size_t vb = (size_t)((b * 12 + h) * 64 + d0) * 4096 + sp;
          vt[vb]          = f2bfu(v[0]);
          vt[vb + 4096]   = f2bfu(v[1]);
          vt[vb + 2*4096] = f2bfu(v[2]);
          vt[vb + 3*4096] = f2bfu(v[3]);
        } else {
          f32x4 sv = *(const f32x4*)(sn + (s << 6) + d0);
          f32x4 cv = *(const f32x4*)(cs + (s << 6) + d0);
          float o0 = v[0] * cv[0] - v[1] * sv[0];
          float o1 = v[1] * cv[0] + v[0] * sv[0];
          float o2 = v[2] * cv[2] - v[3] * sv[2];
          float o3 = v[3] * cv[2] + v[2] * sv[2];
          ushort4 o;
          if (region == 0) {
            o.x = f2bfu(o0 * 0.125f); o.y = f2bfu(o1 * 0.125f);
            o.z = f2bfu(o2 * 0.125f); o.w = f2bfu(o3 * 0.125f);
            *(ushort4*)(qbuf + ((size_t)((b * 12 + h) * 4096 + s)) * 64 + d0) = o;
          } else {
            o.x = f2bfu(o0); o.y = f2bfu(o1); o.z = f2bfu(o2); o.w = f2bfu(o3);
            *(ushort4*)(kbuf + ((size_t)((b * 12 + h) * 4096 + s)) * 64 + d0) = o;
          }
        }
      }
    }
  }
}

// ======== GEMM2: in-block split-K=2, two m97 cores + staged LDS reduce ====
__global__ __launch_bounds__(512, 2) void gemm2_k(const ushort* __restrict__ A,
    const ushort* __restrict__ Bt, const float* __restrict__ bias,
    float* __restrict__ out) {
  __shared__ __align__(16) ushort lds[2][2][128 * 64];  // [grp][A/B] 64KB
  const int t = threadIdx.x;
  const int grp = t >> 8, tl = t & 255;
  const int lane = tl & 63, w4 = tl >> 6;
  const int wr = w4 >> 1, wc = w4 & 1;
  int bid = blockIdx.x;                     // 384 = 8 * 48
  int xcd = bid & 7, local = bid >> 3;
  int g = local / 4, r4 = local % 4;
  int bx = (g % 3) * 2 + (r4 & 1);
  int by = xcd * 8 + (g / 3) * 2 + (r4 >> 1);
  const int mBase = by * 128, nBase = bx * 128;
  const int kOff = grp * 1920;

  size_t gA[4], gB[4];
  int ldst[4];
#pragma unroll
  for (int j = 0; j < 4; ++j) {
    int row = w4 * 32 + j * 8 + (lane >> 3);
    int gc = ((lane & 7) ^ (lane >> 3)) * 8;
    gA[j] = (size_t)(mBase + row) * 3840 + kOff + gc;
    gB[j] = (size_t)(nBase + row) * 3840 + kOff + gc;
    ldst[j] = (w4 * 32 + j * 8) * 64;
  }

  f32x4 acc[4][4];
  f32x4 z = {0.f, 0.f, 0.f, 0.f};
#pragma unroll
  for (int m = 0; m < 4; ++m)
#pragma unroll
    for (int nn = 0; nn < 4; ++nn) acc[m][nn] = z;

#pragma unroll 1
  for (int kt = 0; kt < 30; ++kt) {
    const int k0 = kt * 64;
    __syncthreads();
#pragma unroll
    for (int j = 0; j < 4; ++j) {
      gl_lds16(A + gA[j] + k0, &lds[grp][0][0] + ldst[j]);
      gl_lds16(Bt + gB[j] + k0, &lds[grp][1][0] + ldst[j]);
    }
    __syncthreads();
#pragma unroll
    for (int kk = 0; kk < 2; ++kk) {
      bf16x8 af[4], bff[4];
#pragma unroll
      for (int m = 0; m < 4; ++m) {
        int row = wr * 64 + m * 16 + (lane & 15);
        int slot = (kk * 4 + (lane >> 4)) ^ (lane & 7);
        af[m] = *(const bf16x8*)(&lds[grp][0][0] + row * 64 + slot * 8);
      }
#pragma unroll
      for (int nn = 0; nn < 4; ++nn) {
        int row = wc * 64 + nn * 16 + (lane & 15);
        int slot = (kk * 4 + (lane >> 4)) ^ (lane & 7);
        bff[nn] = *(const bf16x8*)(&lds[grp][1][0] + row * 64 + slot * 8);
      }
#pragma unroll
      for (int m = 0; m < 4; ++m)
#pragma unroll
        for (int nn = 0; nn < 4; ++nn)
          acc[m][nn] = __builtin_amdgcn_mfma_f32_16x16x32_bf16(bff[nn], af[m], acc[m][nn], 0, 0, 0);
    }
  }

  f32x4* sc = (f32x4*)&lds[0][0][0];
#pragma unroll
  for (int h = 0; h < 2; ++h) {
    __syncthreads();
    if (grp == 1) {
#pragma unroll
      for (int m = 0; m < 2; ++m)
#pragma unroll
        for (int nn = 0; nn < 4; ++nn)
          sc[(size_t)tl * 8 + m * 4 + nn] = acc[2 * h + m][nn];
    }
    __syncthreads();
    if (grp == 0) {
#pragma unroll
      for (int m = 0; m < 2; ++m) {
        int row = mBase + wr * 64 + (2 * h + m) * 16 + (lane & 15);
#pragma unroll
        for (int nn = 0; nn < 4; ++nn) {
          int col = nBase + wc * 64 + nn * 16 + ((lane >> 4) << 2);
          f32x4 v = acc[2 * h + m][nn] + sc[(size_t)tl * 8 + m * 4 + nn]
                  + *(const f32x4*)(bias + col);
          *(f32x4*)(out + (size_t)row * 768 + col) = v;
        }
      }
    }
  }
}

// ======== windowed attention: swapped QK^T, P in-register, V pi-permuted ===
__global__ __launch_bounds__(256, 2) void attn_k(const ushort* __restrict__ qb,
    const ushort* __restrict__ kb, const ushort* __restrict__ vt,
    ushort* __restrict__ comb) {
  __shared__ __align__(16) ushort KS[2][128 * 64];
  __shared__ __align__(16) ushort VS[2][64 * 128];
  int bid = blockIdx.x;                      // 768 = 8 * 96
  int nb = (bid & 7) * 96 + (bid >> 3);
  int qt = nb & 31, bh = nb >> 5;
  const int t = threadIdx.x, lane = t & 63, w = t >> 6;
  const int g = lane >> 4, q15 = lane & 15;
  const int qlo = qt * 128;
  const size_t base = (size_t)bh * 4096 * 64;

  size_t kSrc[4], vSrc[4];
  int dstOff[4];
#pragma unroll
  for (int j = 0; j < 4; ++j) {
    int ck = (w * 4 + j) * 64 + lane;
    int key = ck >> 3, sl = ck & 7;
    kSrc[j] = (size_t)key * 64 + ((sl ^ (key & 7)) << 3);
    int dd = ck >> 4, s16 = ck & 15;
    vSrc[j] = (size_t)dd * 4096 + ((s16 ^ (dd & 15)) << 3);
    dstOff[j] = (w * 4 + j) * 512;
  }

  bf16x8 qa[2][2];
#pragma unroll
  for (int m = 0; m < 2; ++m)
#pragma unroll
    for (int kk = 0; kk < 2; ++kk) {
      int row = qlo + w * 32 + m * 16 + q15;
      qa[m][kk] = *(const bf16x8*)(qb + base + (size_t)row * 64 + kk * 32 + g * 8);
    }

  f32x4 z = {0.f, 0.f, 0.f, 0.f};
  f32x4 o[2][4];
#pragma unroll
  for (int m = 0; m < 2; ++m)
#pragma unroll
    for (int df = 0; df < 4; ++df) o[m][df] = z;
  float m_run[2] = {-1e30f, -1e30f}, l_run[2] = {0.f, 0.f};

  const int t0 = qt >= 4 ? qt - 4 : 0;
  const int nt = qt - t0 + 1;
  {
    int k0 = t0 * 128;
#pragma unroll
    for (int j = 0; j < 4; ++j) {
      gl_lds16(kb + base + (size_t)k0 * 64 + kSrc[j], &KS[0][0] + dstOff[j]);
      gl_lds16(vt + base + k0 + vSrc[j], &VS[0][0] + dstOff[j]);
    }
  }

  const int qrow0 = qlo + w * 32 + q15;
#pragma unroll 1
  for (int it = 0; it < nt; ++it) {
    const int kt = t0 + it, k0 = kt * 128, cur = it & 1;
    if (it + 1 < nt) {
      int k1 = k0 + 128;
#pragma unroll
      for (int j = 0; j < 4; ++j) {
        gl_lds16(kb + base + (size_t)k1 * 64 + kSrc[j], &KS[1 - cur][0] + dstOff[j]);
        gl_lds16(vt + base + k1 + vSrc[j], &VS[1 - cur][0] + dstOff[j]);
      }
      WAIT_VM8;
    } else {
      WAIT_VM0;
    }
    BAR;
    f32x4 s[2][8];
#pragma unroll
    for (int m = 0; m < 2; ++m)
#pragma unroll
      for (int nn = 0; nn < 8; ++nn) s[m][nn] = z;
#pragma unroll
    for (int kk = 0; kk < 2; ++kk) {
      bf16x8 kf[8];
#pragma unroll
      for (int nn = 0; nn < 8; ++nn) {
        int row = nn * 16 + q15;
        int slot = (kk * 4 + g) ^ (q15 & 7);
        kf[nn] = *(const bf16x8*)(&KS[cur][0] + row * 64 + slot * 8);
      }
#pragma unroll
      for (int m = 0; m < 2; ++m)
#pragma unroll
        for (int nn = 0; nn < 8; ++nn)
          s[m][nn] = __builtin_amdgcn_mfma_f32_16x16x32_bf16(kf[nn], qa[m][kk], s[m][nn], 0, 0, 0);
    }
    if (kt == qt) {
#pragma unroll
      for (int m = 0; m < 2; ++m) {
        int ql = qrow0 + m * 16 - k0;
#pragma unroll
        for (int nn = 0; nn < 8; ++nn)
#pragma unroll
          for (int r = 0; r < 4; ++r)
            if (nn * 16 + g * 4 + r > ql) s[m][nn][r] = -3e38f;
      }
    } else if (kt == qt - 4) {
#pragma unroll
      for (int m = 0; m < 2; ++m) {
        int ql = qrow0 + m * 16 - k0;
#pragma unroll
        for (int nn = 0; nn < 8; ++nn)
#pragma unroll
          for (int r = 0; r < 4; ++r)
            if (ql - (nn * 16 + g * 4 + r) >= 512) s[m][nn][r] = -3e38f;
      }
    }
    float mx[2];
    bool need = false;
#pragma unroll
    for (int m = 0; m < 2; ++m) {
      float v = s[m][0][0];
#pragma unroll
      for (int nn = 0; nn < 8; ++nn)
#pragma unroll
        for (int r = 0; r < 4; ++r) v = fmaxf(v, s[m][nn][r]);
      v = fmaxf(v, __shfl_xor(v, 16, 64));
      v = fmaxf(v, __shfl_xor(v, 32, 64));
      mx[m] = v;
      need |= (v > m_run[m] + 8.f);
    }
    if (__any(need)) {
#pragma unroll
      for (int m = 0; m < 2; ++m) {
        float mn = fmaxf(m_run[m], mx[m]);
        float sc = exp2f((m_run[m] - mn) * LOG2E);
        m_run[m] = mn;
        l_run[m] *= sc;
#pragma unroll
        for (int df = 0; df < 4; ++df) o[m][df] *= sc;
      }
    }
#pragma unroll
    for (int m = 0; m < 2; ++m) {
      float mr = m_run[m];
      float ls = 0.f;
#pragma unroll
      for (int nn = 0; nn < 8; ++nn)
#pragma unroll
        for (int r = 0; r < 4; ++r) {
          float p = exp2f((s[m][nn][r] - mr) * LOG2E);
          s[m][nn][r] = p;
          ls += p;
        }
      ls += __shfl_xor(ls, 16, 64);
      ls += __shfl_xor(ls, 32, 64);
      l_run[m] += ls;
    }
#pragma unroll
    for (int kk2 = 0; kk2 < 4; ++kk2) {
      bf16x8 pa[2];
#pragma unroll
      for (int m = 0; m < 2; ++m) {
        int4 pi4;
        pi4.x = (int)packbf2(s[m][2*kk2][0],   s[m][2*kk2][1]);
        pi4.y = (int)packbf2(s[m][2*kk2][2],   s[m][2*kk2][3]);
        pi4.z = (int)packbf2(s[m][2*kk2+1][0], s[m][2*kk2+1][1]);
        pi4.w = (int)packbf2(s[m][2*kk2+1][2], s[m][2*kk2+1][3]);
        pa[m] = __builtin_bit_cast(bf16x8, pi4);
      }
#pragma unroll
      for (int df = 0; df < 4; ++df) {
        int row = df * 16 + q15;
        int slot = (kk2 * 4 + g) ^ q15;
        bf16x8 vf = *(const bf16x8*)(&VS[cur][0] + row * 128 + slot * 8);
#pragma unroll
        for (int m = 0; m < 2; ++m)
          o[m][df] = __builtin_amdgcn_mfma_f32_16x16x32_bf16(vf, pa[m], o[m][df], 0, 0, 0);
      }
    }
    WAIT_LGKM;
    BAR;
  }

  int b = bh / 12, h = bh % 12;
#pragma unroll
  for (int m = 0; m < 2; ++m) {
    float inv = 1.0f / l_run[m];
    int row = qrow0 + m * 16;
#pragma unroll
    for (int df = 0; df < 4; ++df) {
      ushort4 ov;
      ov.x = f2bfu(o[m][df][0] * inv);
      ov.y = f2bfu(o[m][df][1] * inv);
      ov.z = f2bfu(o[m][df][2] * inv);
      ov.w = f2bfu(o[m][df][3] * inv);
      *(ushort4*)(comb + (size_t)(b * 4096 + row) * 3840 + h * 64 + df * 16 + g * 4) = ov;
    }
  }
}

extern "C" void kernel_launch(void* const* d_in, const int* in_sizes, int n_in,
                              void* d_out, int out_size, void* d_ws, size_t ws_size,
                              hipStream_t stream) {
  (void)in_sizes; (void)n_in; (void)out_size; (void)ws_size;
  const float* x      = (const float*)d_in[0];
  const float* sin_t  = (const float*)d_in[1];
  const float* cos_t  = (const float*)d_in[2];
  const float* w_norm = (const float*)d_in[3];
  const float* W_in   = (const float*)d_in[4];
  const float* b_in   = (const float*)d_in[5];
  const float* W_out  = (const float*)d_in[6];
  const float* b_out  = (const float*)d_in[7];
  float* out = (float*)d_out;

  const size_t XN_E  = (size_t)8192 * 768;
  ushort* xn      = (ushort*)d_ws;
  ushort* qbuf    = xn + XN_E;
  ushort* kbuf    = qbuf + QKV_E;
  ushort* vt      = kbuf + QKV_E;
  ushort* w_in_t  = vt + QKV_E;
  ushort* w_out_t = w_in_t + (size_t)5376 * 768;
  ushort* comb    = w_out_t + (size_t)768 * 3840;

  rmsnorm_k<<<dim3(8192), dim3(256), 0, stream>>>(x, w_norm, xn);
  tcvt_k<<<dim3(5376 / 32, 768 / 32), dim3(256), 0, stream>>>(W_in, w_in_t, 768, 5376);
  tcvt_k<<<dim3(768 / 32, 3840 / 32), dim3(256), 0, stream>>>(W_out, w_out_t, 3840, 768);
  gemm1_k<<<dim3(2688), dim3(256), 0, stream>>>(xn, w_in_t, b_in, sin_t, cos_t,
                                                qbuf, kbuf, vt, comb);
  attn_k<<<dim3(768), dim3(256), 0, stream>>>(qbuf, kbuf, vt, comb);
  gemm2_k<<<dim3(384), dim3(512), 0, stream>>>(comb, w_out_t, b_out, out);
}

// Round 15
// 221.114 us; speedup vs baseline: 1.9434x; 1.0157x over previous
//
#include <hip/hip_runtime.h>
#include <hip/hip_bf16.h>

typedef short bf16x8 __attribute__((ext_vector_type(8)));
typedef float f32x4 __attribute__((ext_vector_type(4)));

#define LOG2E 1.4426950408889634f
#define QKV_E ((size_t)24*4096*64)

__device__ __forceinline__ float bfu2f(unsigned short u) {
  unsigned v = ((unsigned)u) << 16;
  return __builtin_bit_cast(float, v);
}
__device__ __forceinline__ unsigned short f2bfu(float f) {
  unsigned u = __builtin_bit_cast(unsigned, f);
  u += 0x7fffu + ((u >> 16) & 1u);
  return (unsigned short)(u >> 16);
}
__device__ __forceinline__ unsigned packbf2(float lo, float hi) {
  return (unsigned)f2bfu(lo) | ((unsigned)f2bfu(hi) << 16);
}
__device__ __forceinline__ float gelu_f(float v) {
  float a = fabsf(v) * 0.70710678118654752f;
  float t = 1.0f / (1.0f + 0.3275911f * a);
  float poly = ((((1.061405429f * t - 1.453152027f) * t + 1.421413741f) * t
                 - 0.284496736f) * t + 0.254829592f) * t;
  float erfa = 1.0f - poly * __expf(-a * a);
  float erfv = v >= 0.0f ? erfa : -erfa;
  return 0.5f * v * (1.0f + erfv);
}
__device__ __forceinline__ void gl_lds16(const ushort* g, ushort* l) {
  __builtin_amdgcn_global_load_lds(
      (const __attribute__((address_space(1))) unsigned int*)(const void*)g,
      (__attribute__((address_space(3))) unsigned int*)(void*)l, 16, 0, 0);
}
#define WAIT_VM8  asm volatile("s_waitcnt vmcnt(8)" ::: "memory")
#define WAIT_VM0  asm volatile("s_waitcnt vmcnt(0)" ::: "memory")
#define WAIT_LGKM asm volatile("s_waitcnt lgkmcnt(0)" ::: "memory")
#define BAR       __builtin_amdgcn_s_barrier()

// ---------------- RMSNorm: 1 wave per row, 4 rows/block, no LDS -----------
__global__ __launch_bounds__(256) void rmsnorm_k(const float* __restrict__ x,
    const float* __restrict__ w, ushort* __restrict__ xn) {
  const int wv = threadIdx.x >> 6, lane = threadIdx.x & 63;
  const int row = blockIdx.x * 4 + wv;
  const float* xr = x + (size_t)row * 768;
  f32x4 v0 = *(const f32x4*)(xr + lane * 4);
  f32x4 v1 = *(const f32x4*)(xr + 256 + lane * 4);
  f32x4 v2 = *(const f32x4*)(xr + 512 + lane * 4);
  float ss = v0[0]*v0[0] + v0[1]*v0[1] + v0[2]*v0[2] + v0[3]*v0[3]
           + v1[0]*v1[0] + v1[1]*v1[1] + v1[2]*v1[2] + v1[3]*v1[3]
           + v2[0]*v2[0] + v2[1]*v2[1] + v2[2]*v2[2] + v2[3]*v2[3];
#pragma unroll
  for (int m = 32; m >= 1; m >>= 1) ss += __shfl_xor(ss, m, 64);
  float rr = rsqrtf(ss * (1.0f / 768.0f) + 1e-6f);
  ushort* xo = xn + (size_t)row * 768;
#pragma unroll
  for (int i = 0; i < 3; ++i) {
    f32x4 vv = i == 0 ? v0 : (i == 1 ? v1 : v2);
    f32x4 wv4 = *(const f32x4*)(w + i * 256 + lane * 4);
    ushort4 o;
    o.x = f2bfu(vv[0] * rr * wv4[0]);
    o.y = f2bfu(vv[1] * rr * wv4[1]);
    o.z = f2bfu(vv[2] * rr * wv4[2]);
    o.w = f2bfu(vv[3] * rr * wv4[3]);
    *(ushort4*)(xo + i * 256 + lane * 4) = o;
  }
}

// ------------- fused transpose + fp32->bf16 for BOTH weights --------------
__global__ __launch_bounds__(256) void tcvt_k(const float* __restrict__ W_in,
    const float* __restrict__ W_out, ushort* __restrict__ w_in_t,
    ushort* __restrict__ w_out_t) {
  __shared__ float tile[32][33];
  int bid = blockIdx.x;          // 4032 W_in tiles + 2880 W_out tiles
  const float* in; ushort* out; int R, C, bx, by;
  if (bid < 4032) { in = W_in;  out = w_in_t;  R = 768;  C = 5376; bx = bid % 168; by = bid / 168; }
  else { bid -= 4032; in = W_out; out = w_out_t; R = 3840; C = 768; bx = bid % 24;  by = bid / 24; }
  int c0 = bx * 32, r0 = by * 32;
  int t = threadIdx.x;
  int j = t & 31, i0 = t >> 5;
#pragma unroll
  for (int i = i0; i < 32; i += 8) tile[i][j] = in[(size_t)(r0 + i) * C + c0 + j];
  __syncthreads();
#pragma unroll
  for (int i = i0; i < 32; i += 8) out[(size_t)(c0 + i) * R + r0 + j] = f2bfu(tile[j][i]);
}

// ======== GEMM1: 128x128, m97-style single-buffer, 4 blocks/CU ============
__global__ __launch_bounds__(256, 4) void gemm1_k(const ushort* __restrict__ A,
    const ushort* __restrict__ Bt, const float* __restrict__ bias,
    const float* __restrict__ sn, const float* __restrict__ cs,
    ushort* __restrict__ qbuf, ushort* __restrict__ kbuf,
    ushort* __restrict__ vt, ushort* __restrict__ comb) {
  __shared__ __align__(16) ushort lds[2][128 * 64];   // 32 KB: [A|B]
  const int t = threadIdx.x, lane = t & 63, w = t >> 6;
  const int wr = w >> 1, wc = w & 1;
  int bid = blockIdx.x;                       // 2688 = 8 * 336
  int xcd = bid & 7, local = bid >> 3;
  int grp = local / 48, r6 = local % 48;
  int bx = grp * 6 + r6 % 6;
  int by = xcd * 8 + r6 / 6;
  const int mBase = by * 128, nBase = bx * 128;

  size_t gA[4], gB[4];
  int ldst[4];
#pragma unroll
  for (int j = 0; j < 4; ++j) {
    int row = w * 32 + j * 8 + (lane >> 3);
    int gc = ((lane & 7) ^ (lane >> 3)) * 8;
    gA[j] = (size_t)(mBase + row) * 768 + gc;
    gB[j] = (size_t)(nBase + row) * 768 + gc;
    ldst[j] = (w * 32 + j * 8) * 64;
  }

  f32x4 acc[4][4];
  f32x4 z = {0.f, 0.f, 0.f, 0.f};
#pragma unroll
  for (int m = 0; m < 4; ++m)
#pragma unroll
    for (int nn = 0; nn < 4; ++nn) acc[m][nn] = z;

#pragma unroll 1
  for (int kt = 0; kt < 12; ++kt) {
    const int k0 = kt * 64;
    __syncthreads();
#pragma unroll
    for (int j = 0; j < 4; ++j) {
      gl_lds16(A + gA[j] + k0, &lds[0][0] + ldst[j]);
      gl_lds16(Bt + gB[j] + k0, &lds[1][0] + ldst[j]);
    }
    __syncthreads();
#pragma unroll
    for (int kk = 0; kk < 2; ++kk) {
      bf16x8 af[4], bff[4];
#pragma unroll
      for (int m = 0; m < 4; ++m) {
        int row = wr * 64 + m * 16 + (lane & 15);
        int slot = (kk * 4 + (lane >> 4)) ^ (lane & 7);
        af[m] = *(const bf16x8*)(&lds[0][0] + row * 64 + slot * 8);
      }
#pragma unroll
      for (int nn = 0; nn < 4; ++nn) {
        int row = wc * 64 + nn * 16 + (lane & 15);
        int slot = (kk * 4 + (lane >> 4)) ^ (lane & 7);
        bff[nn] = *(const bf16x8*)(&lds[1][0] + row * 64 + slot * 8);
      }
#pragma unroll
      for (int m = 0; m < 4; ++m)
#pragma unroll
        for (int nn = 0; nn < 4; ++nn)
          acc[m][nn] = __builtin_amdgcn_mfma_f32_16x16x32_bf16(bff[nn], af[m], acc[m][nn], 0, 0, 0);
    }
  }

  const bool isff = (nBase >= 2304);
  const int region = nBase / 768;
#pragma unroll
  for (int m = 0; m < 4; ++m) {
    int row = mBase + wr * 64 + m * 16 + (lane & 15);
    int b = row >> 12, s = row & 4095;
#pragma unroll
    for (int nn = 0; nn < 4; ++nn) {
      int col = nBase + wc * 64 + nn * 16 + ((lane >> 4) << 2);
      f32x4 v = acc[m][nn] + *(const f32x4*)(bias + col);
      if (isff) {
        ushort4 o;
        o.x = f2bfu(gelu_f(v[0]));
        o.y = f2bfu(gelu_f(v[1]));
        o.z = f2bfu(gelu_f(v[2]));
        o.w = f2bfu(gelu_f(v[3]));
        *(ushort4*)(comb + (size_t)row * 3840 + (col - 1536)) = o;
      } else {
        int rem = col - region * 768;
        int h = rem >> 6, d0 = rem & 63;
        if (region == 2) {
          int l = s & 127;
          int pnn = l >> 4, pg = (l >> 2) & 3, pr = l & 3;
          int sp = (s & ~127) | (((pnn >> 1) * 4 + pg) * 8 + (pnn & 1) * 4 + pr);
          size_t vb = (size_t)((b * 12 + h) * 64 + d0) * 4096 + sp;
          vt[vb]          = f2bfu(v[0]);
          vt[vb + 4096]   = f2bfu(v[1]);
          vt[vb + 2*4096] = f2bfu(v[2]);
          vt[vb + 3*4096] = f2bfu(v[3]);
        } else {
          f32x4 sv = *(const f32x4*)(sn + (s << 6) + d0);
          f32x4 cv = *(const f32x4*)(cs + (s << 6) + d0);
          float o0 = v[0] * cv[0] - v[1] * sv[0];
          float o1 = v[1] * cv[0] + v[0] * sv[0];
          float o2 = v[2] * cv[2] - v[3] * sv[2];
          float o3 = v[3] * cv[2] + v[2] * sv[2];
          ushort4 o;
          if (region == 0) {
            o.x = f2bfu(o0 * 0.125f); o.y = f2bfu(o1 * 0.125f);
            o.z = f2bfu(o2 * 0.125f); o.w = f2bfu(o3 * 0.125f);
            *(ushort4*)(qbuf + ((size_t)((b * 12 + h) * 4096 + s)) * 64 + d0) = o;
          } else {
            o.x = f2bfu(o0); o.y = f2bfu(o1); o.z = f2bfu(o2); o.w = f2bfu(o3);
            *(ushort4*)(kbuf + ((size_t)((b * 12 + h) * 4096 + s)) * 64 + d0) = o;
          }
        }
      }
    }
  }
}

// ======== GEMM2: in-block split-K=2, two m97 cores + staged LDS reduce ====
__global__ __launch_bounds__(512, 2) void gemm2_k(const ushort* __restrict__ A,
    const ushort* __restrict__ Bt, const float* __restrict__ bias,
    float* __restrict__ out) {
  __shared__ __align__(16) ushort lds[2][2][128 * 64];  // [grp][A/B] 64KB
  const int t = threadIdx.x;
  const int grp = t >> 8, tl = t & 255;
  const int lane = tl & 63, w4 = tl >> 6;
  const int wr = w4 >> 1, wc = w4 & 1;
  int bid = blockIdx.x;                     // 384 = 8 * 48
  int xcd = bid & 7, local = bid >> 3;
  int g = local / 4, r4 = local % 4;
  int bx = (g % 3) * 2 + (r4 & 1);
  int by = xcd * 8 + (g / 3) * 2 + (r4 >> 1);
  const int mBase = by * 128, nBase = bx * 128;
  const int kOff = grp * 1920;

  size_t gA[4], gB[4];
  int ldst[4];
#pragma unroll
  for (int j = 0; j < 4; ++j) {
    int row = w4 * 32 + j * 8 + (lane >> 3);
    int gc = ((lane & 7) ^ (lane >> 3)) * 8;
    gA[j] = (size_t)(mBase + row) * 3840 + kOff + gc;
    gB[j] = (size_t)(nBase + row) * 3840 + kOff + gc;
    ldst[j] = (w4 * 32 + j * 8) * 64;
  }

  f32x4 acc[4][4];
  f32x4 z = {0.f, 0.f, 0.f, 0.f};
#pragma unroll
  for (int m = 0; m < 4; ++m)
#pragma unroll
    for (int nn = 0; nn < 4; ++nn) acc[m][nn] = z;

#pragma unroll 1
  for (int kt = 0; kt < 30; ++kt) {
    const int k0 = kt * 64;
    __syncthreads();
#pragma unroll
    for (int j = 0; j < 4; ++j) {
      gl_lds16(A + gA[j] + k0, &lds[grp][0][0] + ldst[j]);
      gl_lds16(Bt + gB[j] + k0, &lds[grp][1][0] + ldst[j]);
    }
    __syncthreads();
#pragma unroll
    for (int kk = 0; kk < 2; ++kk) {
      bf16x8 af[4], bff[4];
#pragma unroll
      for (int m = 0; m < 4; ++m) {
        int row = wr * 64 + m * 16 + (lane & 15);
        int slot = (kk * 4 + (lane >> 4)) ^ (lane & 7);
        af[m] = *(const bf16x8*)(&lds[grp][0][0] + row * 64 + slot * 8);
      }
#pragma unroll
      for (int nn = 0; nn < 4; ++nn) {
        int row = wc * 64 + nn * 16 + (lane & 15);
        int slot = (kk * 4 + (lane >> 4)) ^ (lane & 7);
        bff[nn] = *(const bf16x8*)(&lds[grp][1][0] + row * 64 + slot * 8);
      }
#pragma unroll
      for (int m = 0; m < 4; ++m)
#pragma unroll
        for (int nn = 0; nn < 4; ++nn)
          acc[m][nn] = __builtin_amdgcn_mfma_f32_16x16x32_bf16(bff[nn], af[m], acc[m][nn], 0, 0, 0);
    }
  }

  f32x4* sc = (f32x4*)&lds[0][0][0];
#pragma unroll
  for (int h = 0; h < 2; ++h) {
    __syncthreads();
    if (grp == 1) {
#pragma unroll
      for (int m = 0; m < 2; ++m)
#pragma unroll
        for (int nn = 0; nn < 4; ++nn)
          sc[(size_t)tl * 8 + m * 4 + nn] = acc[2 * h + m][nn];
    }
    __syncthreads();
    if (grp == 0) {
#pragma unroll
      for (int m = 0; m < 2; ++m) {
        int row = mBase + wr * 64 + (2 * h + m) * 16 + (lane & 15);
#pragma unroll
        for (int nn = 0; nn < 4; ++nn) {
          int col = nBase + wc * 64 + nn * 16 + ((lane >> 4) << 2);
          f32x4 v = acc[2 * h + m][nn] + sc[(size_t)tl * 8 + m * 4 + nn]
                  + *(const f32x4*)(bias + col);
          *(f32x4*)(out + (size_t)row * 768 + col) = v;
        }
      }
    }
  }
}

// ======== windowed attention: swapped QK^T, P in-register, V pi-permuted ===
__global__ __launch_bounds__(256, 2) void attn_k(const ushort* __restrict__ qb,
    const ushort* __restrict__ kb, const ushort* __restrict__ vt,
    ushort* __restrict__ comb) {
  __shared__ __align__(16) ushort KS[2][128 * 64];
  __shared__ __align__(16) ushort VS[2][64 * 128];
  int bid = blockIdx.x;                      // 768 = 8 * 96
  int nb = (bid & 7) * 96 + (bid >> 3);
  int qt = nb & 31, bh = nb >> 5;
  const int t = threadIdx.x, lane = t & 63, w = t >> 6;
  const int g = lane >> 4, q15 = lane & 15;
  const int qlo = qt * 128;
  const size_t base = (size_t)bh * 4096 * 64;

  size_t kSrc[4], vSrc[4];
  int dstOff[4];
#pragma unroll
  for (int j = 0; j < 4; ++j) {
    int ck = (w * 4 + j) * 64 + lane;
    int key = ck >> 3, sl = ck & 7;
    kSrc[j] = (size_t)key * 64 + ((sl ^ (key & 7)) << 3);
    int dd = ck >> 4, s16 = ck & 15;
    vSrc[j] = (size_t)dd * 4096 + ((s16 ^ (dd & 15)) << 3);
    dstOff[j] = (w * 4 + j) * 512;
  }

  bf16x8 qa[2][2];
#pragma unroll
  for (int m = 0; m < 2; ++m)
#pragma unroll
    for (int kk = 0; kk < 2; ++kk) {
      int row = qlo + w * 32 + m * 16 + q15;
      qa[m][kk] = *(const bf16x8*)(qb + base + (size_t)row * 64 + kk * 32 + g * 8);
    }

  f32x4 z = {0.f, 0.f, 0.f, 0.f};
  f32x4 o[2][4];
#pragma unroll
  for (int m = 0; m < 2; ++m)
#pragma unroll
    for (int df = 0; df < 4; ++df) o[m][df] = z;
  float m_run[2] = {-1e30f, -1e30f}, l_run[2] = {0.f, 0.f};

  const int t0 = qt >= 4 ? qt - 4 : 0;
  const int nt = qt - t0 + 1;
  {
    int k0 = t0 * 128;
#pragma unroll
    for (int j = 0; j < 4; ++j) {
      gl_lds16(kb + base + (size_t)k0 * 64 + kSrc[j], &KS[0][0] + dstOff[j]);
      gl_lds16(vt + base + k0 + vSrc[j], &VS[0][0] + dstOff[j]);
    }
  }

  const int qrow0 = qlo + w * 32 + q15;
#pragma unroll 1
  for (int it = 0; it < nt; ++it) {
    const int kt = t0 + it, k0 = kt * 128, cur = it & 1;
    if (it + 1 < nt) {
      int k1 = k0 + 128;
#pragma unroll
      for (int j = 0; j < 4; ++j) {
        gl_lds16(kb + base + (size_t)k1 * 64 + kSrc[j], &KS[1 - cur][0] + dstOff[j]);
        gl_lds16(vt + base + k1 + vSrc[j], &VS[1 - cur][0] + dstOff[j]);
      }
      WAIT_VM8;
    } else {
      WAIT_VM0;
    }
    BAR;
    f32x4 s[2][8];
#pragma unroll
    for (int m = 0; m < 2; ++m)
#pragma unroll
      for (int nn = 0; nn < 8; ++nn) s[m][nn] = z;
#pragma unroll
    for (int kk = 0; kk < 2; ++kk) {
      bf16x8 kf[8];
#pragma unroll
      for (int nn = 0; nn < 8; ++nn) {
        int row = nn * 16 + q15;
        int slot = (kk * 4 + g) ^ (q15 & 7);
        kf[nn] = *(const bf16x8*)(&KS[cur][0] + row * 64 + slot * 8);
      }
#pragma unroll
      for (int m = 0; m < 2; ++m)
#pragma unroll
        for (int nn = 0; nn < 8; ++nn)
          s[m][nn] = __builtin_amdgcn_mfma_f32_16x16x32_bf16(kf[nn], qa[m][kk], s[m][nn], 0, 0, 0);
    }
    if (kt == qt) {
#pragma unroll
      for (int m = 0; m < 2; ++m) {
        int ql = qrow0 + m * 16 - k0;
#pragma unroll
        for (int nn = 0; nn < 8; ++nn)
#pragma unroll
          for (int r = 0; r < 4; ++r)
            if (nn * 16 + g * 4 + r > ql) s[m][nn][r] = -3e38f;
      }
    } else if (kt == qt - 4) {
#pragma unroll
      for (int m = 0; m < 2; ++m) {
        int ql = qrow0 + m * 16 - k0;
#pragma unroll
        for (int nn = 0; nn < 8; ++nn)
#pragma unroll
          for (int r = 0; r < 4; ++r)
            if (ql - (nn * 16 + g * 4 + r) >= 512) s[m][nn][r] = -3e38f;
      }
    }
    float mx[2];
    bool need = false;
#pragma unroll
    for (int m = 0; m < 2; ++m) {
      float v = s[m][0][0];
#pragma unroll
      for (int nn = 0; nn < 8; ++nn)
#pragma unroll
        for (int r = 0; r < 4; ++r) v = fmaxf(v, s[m][nn][r]);
      v = fmaxf(v, __shfl_xor(v, 16, 64));
      v = fmaxf(v, __shfl_xor(v, 32, 64));
      mx[m] = v;
      need |= (v > m_run[m] + 8.f);
    }
    if (__any(need)) {
#pragma unroll
      for (int m = 0; m < 2; ++m) {
        float mn = fmaxf(m_run[m], mx[m]);
        float sc = exp2f((m_run[m] - mn) * LOG2E);
        m_run[m] = mn;
        l_run[m] *= sc;
#pragma unroll
        for (int df = 0; df < 4; ++df) o[m][df] *= sc;
      }
    }
#pragma unroll
    for (int m = 0; m < 2; ++m) {
      float mr = m_run[m];
      float ls = 0.f;
#pragma unroll
      for (int nn = 0; nn < 8; ++nn)
#pragma unroll
        for (int r = 0; r < 4; ++r) {
          float p = exp2f((s[m][nn][r] - mr) * LOG2E);
          s[m][nn][r] = p;
          ls += p;
        }
      ls += __shfl_xor(ls, 16, 64);
      ls += __shfl_xor(ls, 32, 64);
      l_run[m] += ls;
    }
#pragma unroll
    for (int kk2 = 0; kk2 < 4; ++kk2) {
      bf16x8 pa[2];
#pragma unroll
      for (int m = 0; m < 2; ++m) {
        int4 pi4;
        pi4.x = (int)packbf2(s[m][2*kk2][0],   s[m][2*kk2][1]);
        pi4.y = (int)packbf2(s[m][2*kk2][2],   s[m][2*kk2][3]);
        pi4.z = (int)packbf2(s[m][2*kk2+1][0], s[m][2*kk2+1][1]);
        pi4.w = (int)packbf2(s[m][2*kk2+1][2], s[m][2*kk2+1][3]);
        pa[m] = __builtin_bit_cast(bf16x8, pi4);
      }
#pragma unroll
      for (int df = 0; df < 4; ++df) {
        int row = df * 16 + q15;
        int slot = (kk2 * 4 + g) ^ q15;
        bf16x8 vf = *(const bf16x8*)(&VS[cur][0] + row * 128 + slot * 8);
#pragma unroll
        for (int m = 0; m < 2; ++m)
          o[m][df] = __builtin_amdgcn_mfma_f32_16x16x32_bf16(vf, pa[m], o[m][df], 0, 0, 0);
      }
    }
    WAIT_LGKM;
    BAR;
  }

  int b = bh / 12, h = bh % 12;
#pragma unroll
  for (int m = 0; m < 2; ++m) {
    float inv = 1.0f / l_run[m];
    int row = qrow0 + m * 16;
#pragma unroll
    for (int df = 0; df < 4; ++df) {
      ushort4 ov;
      ov.x = f2bfu(o[m][df][0] * inv);
      ov.y = f2bfu(o[m][df][1] * inv);
      ov.z = f2bfu(o[m][df][2] * inv);
      ov.w = f2bfu(o[m][df][3] * inv);
      *(ushort4*)(comb + (size_t)(b * 4096 + row) * 3840 + h * 64 + df * 16 + g * 4) = ov;
    }
  }
}

extern "C" void kernel_launch(void* const* d_in, const int* in_sizes, int n_in,
                              void* d_out, int out_size, void* d_ws, size_t ws_size,
                              hipStream_t stream) {
  (void)in_sizes; (void)n_in; (void)out_size; (void)ws_size;
  const float* x      = (const float*)d_in[0];
  const float* sin_t  = (const float*)d_in[1];
  const float* cos_t  = (const float*)d_in[2];
  const float* w_norm = (const float*)d_in[3];
  const float* W_in   = (const float*)d_in[4];
  const float* b_in   = (const float*)d_in[5];
  const float* W_out  = (const float*)d_in[6];
  const float* b_out  = (const float*)d_in[7];
  float* out = (float*)d_out;

  const size_t XN_E  = (size_t)8192 * 768;
  ushort* xn      = (ushort*)d_ws;
  ushort* qbuf    = xn + XN_E;
  ushort* kbuf    = qbuf + QKV_E;
  ushort* vt      = kbuf + QKV_E;
  ushort* w_in_t  = vt + QKV_E;
  ushort* w_out_t = w_in_t + (size_t)5376 * 768;
  ushort* comb    = w_out_t + (size_t)768 * 3840;

  rmsnorm_k<<<dim3(2048), dim3(256), 0, stream>>>(x, w_norm, xn);
  tcvt_k<<<dim3(6912), dim3(256), 0, stream>>>(W_in, W_out, w_in_t, w_out_t);
  gemm1_k<<<dim3(2688), dim3(256), 0, stream>>>(xn, w_in_t, b_in, sin_t, cos_t,
                                                qbuf, kbuf, vt, comb);
  attn_k<<<dim3(768), dim3(256), 0, stream>>>(qbuf, kbuf, vt, comb);
  gemm2_k<<<dim3(384), dim3(512), 0, stream>>>(comb, w_out_t, b_out, out);
}

// Round 16
// 218.066 us; speedup vs baseline: 1.9706x; 1.0140x over previous
//
#include <hip/hip_runtime.h>
#include <hip/hip_bf16.h>

typedef short bf16x8 __attribute__((ext_vector_type(8)));
typedef float f32x4 __attribute__((ext_vector_type(4)));

#define LOG2E 1.4426950408889634f
#define QKV_E ((size_t)24*4096*64)

__device__ __forceinline__ float bfu2f(unsigned short u) {
  unsigned v = ((unsigned)u) << 16;
  return __builtin_bit_cast(float, v);
}
__device__ __forceinline__ unsigned short f2bfu(float f) {
  unsigned u = __builtin_bit_cast(unsigned, f);
  u += 0x7fffu + ((u >> 16) & 1u);
  return (unsigned short)(u >> 16);
}
__device__ __forceinline__ unsigned packbf2(float lo, float hi) {
  return (unsigned)f2bfu(lo) | ((unsigned)f2bfu(hi) << 16);
}
__device__ __forceinline__ float gelu_f(float v) {
  float a = fabsf(v) * 0.70710678118654752f;
  float t = 1.0f / (1.0f + 0.3275911f * a);
  float poly = ((((1.061405429f * t - 1.453152027f) * t + 1.421413741f) * t
                 - 0.284496736f) * t + 0.254829592f) * t;
  float erfa = 1.0f - poly * __expf(-a * a);
  float erfv = v >= 0.0f ? erfa : -erfa;
  return 0.5f * v * (1.0f + erfv);
}
__device__ __forceinline__ void gl_lds16(const ushort* g, ushort* l) {
  __builtin_amdgcn_global_load_lds(
      (const __attribute__((address_space(1))) unsigned int*)(const void*)g,
      (__attribute__((address_space(3))) unsigned int*)(void*)l, 16, 0, 0);
}
#define WAIT_VM8  asm volatile("s_waitcnt vmcnt(8)" ::: "memory")
#define WAIT_VM0  asm volatile("s_waitcnt vmcnt(0)" ::: "memory")
#define WAIT_LGKM asm volatile("s_waitcnt lgkmcnt(0)" ::: "memory")
#define BAR       __builtin_amdgcn_s_barrier()

// ---- fused prep: blocks 0..2047 rmsnorm (4 rows each); rest: transposes ---
__global__ __launch_bounds__(256) void prep_k(const float* __restrict__ x,
    const float* __restrict__ w, ushort* __restrict__ xn,
    const float* __restrict__ W_in, const float* __restrict__ W_out,
    ushort* __restrict__ w_in_t, ushort* __restrict__ w_out_t) {
  __shared__ float tile[32][33];
  int bid = blockIdx.x;
  if (bid < 2048) {
    const int wv = threadIdx.x >> 6, lane = threadIdx.x & 63;
    const int row = bid * 4 + wv;
    const float* xr = x + (size_t)row * 768;
    f32x4 v0 = *(const f32x4*)(xr + lane * 4);
    f32x4 v1 = *(const f32x4*)(xr + 256 + lane * 4);
    f32x4 v2 = *(const f32x4*)(xr + 512 + lane * 4);
    float ss = v0[0]*v0[0] + v0[1]*v0[1] + v0[2]*v0[2] + v0[3]*v0[3]
             + v1[0]*v1[0] + v1[1]*v1[1] + v1[2]*v1[2] + v1[3]*v1[3]
             + v2[0]*v2[0] + v2[1]*v2[1] + v2[2]*v2[2] + v2[3]*v2[3];
#pragma unroll
    for (int m = 32; m >= 1; m >>= 1) ss += __shfl_xor(ss, m, 64);
    float rr = rsqrtf(ss * (1.0f / 768.0f) + 1e-6f);
    ushort* xo = xn + (size_t)row * 768;
#pragma unroll
    for (int i = 0; i < 3; ++i) {
      f32x4 vv = i == 0 ? v0 : (i == 1 ? v1 : v2);
      f32x4 wv4 = *(const f32x4*)(w + i * 256 + lane * 4);
      ushort4 o;
      o.x = f2bfu(vv[0] * rr * wv4[0]);
      o.y = f2bfu(vv[1] * rr * wv4[1]);
      o.z = f2bfu(vv[2] * rr * wv4[2]);
      o.w = f2bfu(vv[3] * rr * wv4[3]);
      *(ushort4*)(xo + i * 256 + lane * 4) = o;
    }
    return;
  }
  bid -= 2048;                   // 4032 W_in tiles + 2880 W_out tiles
  const float* in; ushort* out; int R, C, bx, by;
  if (bid < 4032) { in = W_in;  out = w_in_t;  R = 768;  C = 5376; bx = bid % 168; by = bid / 168; }
  else { bid -= 4032; in = W_out; out = w_out_t; R = 3840; C = 768; bx = bid % 24;  by = bid / 24; }
  int c0 = bx * 32, r0 = by * 32;
  int t = threadIdx.x;
  int j = t & 31, i0 = t >> 5;
#pragma unroll
  for (int i = i0; i < 32; i += 8) tile[i][j] = in[(size_t)(r0 + i) * C + c0 + j];
  __syncthreads();
#pragma unroll
  for (int i = i0; i < 32; i += 8) out[(size_t)(c0 + i) * R + r0 + j] = f2bfu(tile[j][i]);
}

// ======== GEMM1: 128x128, m97-style single-buffer, 4 blocks/CU ============
__global__ __launch_bounds__(256, 4) void gemm1_k(const ushort* __restrict__ A,
    const ushort* __restrict__ Bt, const float* __restrict__ bias,
    const float* __restrict__ sn, const float* __restrict__ cs,
    ushort* __restrict__ qbuf, ushort* __restrict__ kbuf,
    ushort* __restrict__ vt, ushort* __restrict__ comb) {
  __shared__ __align__(16) ushort lds[2][128 * 64];   // 32 KB: [A|B]
  const int t = threadIdx.x, lane = t & 63, w = t >> 6;
  const int wr = w >> 1, wc = w & 1;
  int bid = blockIdx.x;                       // 2688 = 8 * 336
  int xcd = bid & 7, local = bid >> 3;
  int grp = local / 48, r6 = local % 48;
  int bx = grp * 6 + r6 % 6;
  int by = xcd * 8 + r6 / 6;
  const int mBase = by * 128, nBase = bx * 128;

  size_t gA[4], gB[4];
  int ldst[4];
#pragma unroll
  for (int j = 0; j < 4; ++j) {
    int row = w * 32 + j * 8 + (lane >> 3);
    int gc = ((lane & 7) ^ (lane >> 3)) * 8;
    gA[j] = (size_t)(mBase + row) * 768 + gc;
    gB[j] = (size_t)(nBase + row) * 768 + gc;
    ldst[j] = (w * 32 + j * 8) * 64;
  }

  f32x4 acc[4][4];
  f32x4 z = {0.f, 0.f, 0.f, 0.f};
#pragma unroll
  for (int m = 0; m < 4; ++m)
#pragma unroll
    for (int nn = 0; nn < 4; ++nn) acc[m][nn] = z;

#pragma unroll 1
  for (int kt = 0; kt < 12; ++kt) {
    const int k0 = kt * 64;
    __syncthreads();
#pragma unroll
    for (int j = 0; j < 4; ++j) {
      gl_lds16(A + gA[j] + k0, &lds[0][0] + ldst[j]);
      gl_lds16(Bt + gB[j] + k0, &lds[1][0] + ldst[j]);
    }
    __syncthreads();
#pragma unroll
    for (int kk = 0; kk < 2; ++kk) {
      bf16x8 af[4], bff[4];
#pragma unroll
      for (int m = 0; m < 4; ++m) {
        int row = wr * 64 + m * 16 + (lane & 15);
        int slot = (kk * 4 + (lane >> 4)) ^ (lane & 7);
        af[m] = *(const bf16x8*)(&lds[0][0] + row * 64 + slot * 8);
      }
#pragma unroll
      for (int nn = 0; nn < 4; ++nn) {
        int row = wc * 64 + nn * 16 + (lane & 15);
        int slot = (kk * 4 + (lane >> 4)) ^ (lane & 7);
        bff[nn] = *(const bf16x8*)(&lds[1][0] + row * 64 + slot * 8);
      }
#pragma unroll
      for (int m = 0; m < 4; ++m)
#pragma unroll
        for (int nn = 0; nn < 4; ++nn)
          acc[m][nn] = __builtin_amdgcn_mfma_f32_16x16x32_bf16(bff[nn], af[m], acc[m][nn], 0, 0, 0);
    }
  }

  const bool isff = (nBase >= 2304);
  const int region = nBase / 768;
#pragma unroll
  for (int m = 0; m < 4; ++m) {
    int row = mBase + wr * 64 + m * 16 + (lane & 15);
    int b = row >> 12, s = row & 4095;
#pragma unroll
    for (int nn = 0; nn < 4; ++nn) {
      int col = nBase + wc * 64 + nn * 16 + ((lane >> 4) << 2);
      f32x4 v = acc[m][nn] + *(const f32x4*)(bias + col);
      if (isff) {
        ushort4 o;
        o.x = f2bfu(gelu_f(v[0]));
        o.y = f2bfu(gelu_f(v[1]));
        o.z = f2bfu(gelu_f(v[2]));
        o.w = f2bfu(gelu_f(v[3]));
        *(ushort4*)(comb + (size_t)row * 3840 + (col - 1536)) = o;
      } else {
        int rem = col - region * 768;
        int h = rem >> 6, d0 = rem & 63;
        if (region == 2) {
          int l = s & 127;
          int pnn = l >> 4, pg = (l >> 2) & 3, pr = l & 3;
          int sp = (s & ~127) | (((pnn >> 1) * 4 + pg) * 8 + (pnn & 1) * 4 + pr);
          size_t vb = (size_t)((b * 12 + h) * 64 + d0) * 4096 + sp;
          vt[vb]          = f2bfu(v[0]);
          vt[vb + 4096]   = f2bfu(v[1]);
          vt[vb + 2*4096] = f2bfu(v[2]);
          vt[vb + 3*4096] = f2bfu(v[3]);
        } else {
          f32x4 sv = *(const f32x4*)(sn + (s << 6) + d0);
          f32x4 cv = *(const f32x4*)(cs + (s << 6) + d0);
          float o0 = v[0] * cv[0] - v[1] * sv[0];
          float o1 = v[1] * cv[0] + v[0] * sv[0];
          float o2 = v[2] * cv[2] - v[3] * sv[2];
          float o3 = v[3] * cv[2] + v[2] * sv[2];
          ushort4 o;
          if (region == 0) {
            o.x = f2bfu(o0 * 0.125f); o.y = f2bfu(o1 * 0.125f);
            o.z = f2bfu(o2 * 0.125f); o.w = f2bfu(o3 * 0.125f);
            *(ushort4*)(qbuf + ((size_t)((b * 12 + h) * 4096 + s)) * 64 + d0) = o;
          } else {
            o.x = f2bfu(o0); o.y = f2bfu(o1); o.z = f2bfu(o2); o.w = f2bfu(o3);
            *(ushort4*)(kbuf + ((size_t)((b * 12 + h) * 4096 + s)) * 64 + d0) = o;
          }
        }
      }
    }
  }
}

// ======== GEMM2: in-block split-K=2, two m97 cores + staged LDS reduce ====
__global__ __launch_bounds__(512, 2) void gemm2_k(const ushort* __restrict__ A,
    const ushort* __restrict__ Bt, const float* __restrict__ bias,
    float* __restrict__ out) {
  __shared__ __align__(16) ushort lds[2][2][128 * 64];  // [grp][A/B] 64KB
  const int t = threadIdx.x;
  const int grp = t >> 8, tl = t & 255;
  const int lane = tl & 63, w4 = tl >> 6;
  const int wr = w4 >> 1, wc = w4 & 1;
  int bid = blockIdx.x;                     // 384 = 8 * 48
  int xcd = bid & 7, local = bid >> 3;
  int g = local / 4, r4 = local % 4;
  int bx = (g % 3) * 2 + (r4 & 1);
  int by = xcd * 8 + (g / 3) * 2 + (r4 >> 1);
  const int mBase = by * 128, nBase = bx * 128;
  const int kOff = grp * 1920;

  size_t gA[4], gB[4];
  int ldst[4];
#pragma unroll
  for (int j = 0; j < 4; ++j) {
    int row = w4 * 32 + j * 8 + (lane >> 3);
    int gc = ((lane & 7) ^ (lane >> 3)) * 8;
    gA[j] = (size_t)(mBase + row) * 3840 + kOff + gc;
    gB[j] = (size_t)(nBase + row) * 3840 + kOff + gc;
    ldst[j] = (w4 * 32 + j * 8) * 64;
  }

  f32x4 acc[4][4];
  f32x4 z = {0.f, 0.f, 0.f, 0.f};
#pragma unroll
  for (int m = 0; m < 4; ++m)
#pragma unroll
    for (int nn = 0; nn < 4; ++nn) acc[m][nn] = z;

#pragma unroll 1
  for (int kt = 0; kt < 30; ++kt) {
    const int k0 = kt * 64;
    __syncthreads();
#pragma unroll
    for (int j = 0; j < 4; ++j) {
      gl_lds16(A + gA[j] + k0, &lds[grp][0][0] + ldst[j]);
      gl_lds16(Bt + gB[j] + k0, &lds[grp][1][0] + ldst[j]);
    }
    __syncthreads();
#pragma unroll
    for (int kk = 0; kk < 2; ++kk) {
      bf16x8 af[4], bff[4];
#pragma unroll
      for (int m = 0; m < 4; ++m) {
        int row = wr * 64 + m * 16 + (lane & 15);
        int slot = (kk * 4 + (lane >> 4)) ^ (lane & 7);
        af[m] = *(const bf16x8*)(&lds[grp][0][0] + row * 64 + slot * 8);
      }
#pragma unroll
      for (int nn = 0; nn < 4; ++nn) {
        int row = wc * 64 + nn * 16 + (lane & 15);
        int slot = (kk * 4 + (lane >> 4)) ^ (lane & 7);
        bff[nn] = *(const bf16x8*)(&lds[grp][1][0] + row * 64 + slot * 8);
      }
#pragma unroll
      for (int m = 0; m < 4; ++m)
#pragma unroll
        for (int nn = 0; nn < 4; ++nn)
          acc[m][nn] = __builtin_amdgcn_mfma_f32_16x16x32_bf16(bff[nn], af[m], acc[m][nn], 0, 0, 0);
    }
  }

  f32x4* sc = (f32x4*)&lds[0][0][0];
#pragma unroll
  for (int h = 0; h < 2; ++h) {
    __syncthreads();
    if (grp == 1) {
#pragma unroll
      for (int m = 0; m < 2; ++m)
#pragma unroll
        for (int nn = 0; nn < 4; ++nn)
          sc[(size_t)tl * 8 + m * 4 + nn] = acc[2 * h + m][nn];
    }
    __syncthreads();
    if (grp == 0) {
#pragma unroll
      for (int m = 0; m < 2; ++m) {
        int row = mBase + wr * 64 + (2 * h + m) * 16 + (lane & 15);
#pragma unroll
        for (int nn = 0; nn < 4; ++nn) {
          int col = nBase + wc * 64 + nn * 16 + ((lane >> 4) << 2);
          f32x4 v = acc[2 * h + m][nn] + sc[(size_t)tl * 8 + m * 4 + nn]
                  + *(const f32x4*)(bias + col);
          *(f32x4*)(out + (size_t)row * 768 + col) = v;
        }
      }
    }
  }
}

// ======== windowed attention: swapped QK^T, P in-register, V pi-permuted ===
__global__ __launch_bounds__(256, 2) void attn_k(const ushort* __restrict__ qb,
    const ushort* __restrict__ kb, const ushort* __restrict__ vt,
    ushort* __restrict__ comb) {
  __shared__ __align__(16) ushort KS[2][128 * 64];
  __shared__ __align__(16) ushort VS[2][64 * 128];
  int bid = blockIdx.x;                      // 768 = 8 * 96
  int nb = (bid & 7) * 96 + (bid >> 3);
  int qt = nb & 31, bh = nb >> 5;
  const int t = threadIdx.x, lane = t & 63, w = t >> 6;
  const int g = lane >> 4, q15 = lane & 15;
  const int qlo = qt * 128;
  const size_t base = (size_t)bh * 4096 * 64;

  size_t kSrc[4], vSrc[4];
  int dstOff[4];
#pragma unroll
  for (int j = 0; j < 4; ++j) {
    int ck = (w * 4 + j) * 64 + lane;
    int key = ck >> 3, sl = ck & 7;
    kSrc[j] = (size_t)key * 64 + ((sl ^ (key & 7)) << 3);
    int dd = ck >> 4, s16 = ck & 15;
    vSrc[j] = (size_t)dd * 4096 + ((s16 ^ (dd & 15)) << 3);
    dstOff[j] = (w * 4 + j) * 512;
  }

  bf16x8 qa[2][2];
#pragma unroll
  for (int m = 0; m < 2; ++m)
#pragma unroll
    for (int kk = 0; kk < 2; ++kk) {
      int row = qlo + w * 32 + m * 16 + q15;
      qa[m][kk] = *(const bf16x8*)(qb + base + (size_t)row * 64 + kk * 32 + g * 8);
    }

  f32x4 z = {0.f, 0.f, 0.f, 0.f};
  f32x4 o[2][4];
#pragma unroll
  for (int m = 0; m < 2; ++m)
#pragma unroll
    for (int df = 0; df < 4; ++df) o[m][df] = z;
  float m_run[2] = {-1e30f, -1e30f}, l_run[2] = {0.f, 0.f};

  const int t0 = qt >= 4 ? qt - 4 : 0;
  const int nt = qt - t0 + 1;
  {
    int k0 = t0 * 128;
#pragma unroll
    for (int j = 0; j < 4; ++j) {
      gl_lds16(kb + base + (size_t)k0 * 64 + kSrc[j], &KS[0][0] + dstOff[j]);
      gl_lds16(vt + base + k0 + vSrc[j], &VS[0][0] + dstOff[j]);
    }
  }

  const int qrow0 = qlo + w * 32 + q15;
#pragma unroll 1
  for (int it = 0; it < nt; ++it) {
    const int kt = t0 + it, k0 = kt * 128, cur = it & 1;
    if (it + 1 < nt) {
      int k1 = k0 + 128;
#pragma unroll
      for (int j = 0; j < 4; ++j) {
        gl_lds16(kb + base + (size_t)k1 * 64 + kSrc[j], &KS[1 - cur][0] + dstOff[j]);
        gl_lds16(vt + base + k1 + vSrc[j], &VS[1 - cur][0] + dstOff[j]);
      }
      WAIT_VM8;
    } else {
      WAIT_VM0;
    }
    BAR;
    f32x4 s[2][8];
#pragma unroll
    for (int m = 0; m < 2; ++m)
#pragma unroll
      for (int nn = 0; nn < 8; ++nn) s[m][nn] = z;
#pragma unroll
    for (int kk = 0; kk < 2; ++kk) {
      bf16x8 kf[8];
#pragma unroll
      for (int nn = 0; nn < 8; ++nn) {
        int row = nn * 16 + q15;
        int slot = (kk * 4 + g) ^ (q15 & 7);
        kf[nn] = *(const bf16x8*)(&KS[cur][0] + row * 64 + slot * 8);
      }
#pragma unroll
      for (int m = 0; m < 2; ++m)
#pragma unroll
        for (int nn = 0; nn < 8; ++nn)
          s[m][nn] = __builtin_amdgcn_mfma_f32_16x16x32_bf16(kf[nn], qa[m][kk], s[m][nn], 0, 0, 0);
    }
    if (kt == qt) {
#pragma unroll
      for (int m = 0; m < 2; ++m) {
        int ql = qrow0 + m * 16 - k0;
#pragma unroll
        for (int nn = 0; nn < 8; ++nn)
#pragma unroll
          for (int r = 0; r < 4; ++r)
            if (nn * 16 + g * 4 + r > ql) s[m][nn][r] = -3e38f;
      }
    } else if (kt == qt - 4) {
#pragma unroll
      for (int m = 0; m < 2; ++m) {
        int ql = qrow0 + m * 16 - k0;
#pragma unroll
        for (int nn = 0; nn < 8; ++nn)
#pragma unroll
          for (int r = 0; r < 4; ++r)
            if (ql - (nn * 16 + g * 4 + r) >= 512) s[m][nn][r] = -3e38f;
      }
    }
    float mx[2];
    bool need = false;
#pragma unroll
    for (int m = 0; m < 2; ++m) {
      float v = s[m][0][0];
#pragma unroll
      for (int nn = 0; nn < 8; ++nn)
#pragma unroll
        for (int r = 0; r < 4; ++r) v = fmaxf(v, s[m][nn][r]);
      v = fmaxf(v, __shfl_xor(v, 16, 64));
      v = fmaxf(v, __shfl_xor(v, 32, 64));
      mx[m] = v;
      need |= (v > m_run[m] + 8.f);
    }
    if (__any(need)) {
#pragma unroll
      for (int m = 0; m < 2; ++m) {
        float mn = fmaxf(m_run[m], mx[m]);
        float sc = exp2f((m_run[m] - mn) * LOG2E);
        m_run[m] = mn;
        l_run[m] *= sc;
#pragma unroll
        for (int df = 0; df < 4; ++df) o[m][df] *= sc;
      }
    }
#pragma unroll
    for (int m = 0; m < 2; ++m) {
      float mr = m_run[m];
      float ls = 0.f;
#pragma unroll
      for (int nn = 0; nn < 8; ++nn)
#pragma unroll
        for (int r = 0; r < 4; ++r) {
          float p = exp2f((s[m][nn][r] - mr) * LOG2E);
          s[m][nn][r] = p;
          ls += p;
        }
      ls += __shfl_xor(ls, 16, 64);
      ls += __shfl_xor(ls, 32, 64);
      l_run[m] += ls;
    }
#pragma unroll
    for (int kk2 = 0; kk2 < 4; ++kk2) {
      bf16x8 pa[2];
#pragma unroll
      for (int m = 0; m < 2; ++m) {
        int4 pi4;
        pi4.x = (int)packbf2(s[m][2*kk2][0],   s[m][2*kk2][1]);
        pi4.y = (int)packbf2(s[m][2*kk2][2],   s[m][2*kk2][3]);
        pi4.z = (int)packbf2(s[m][2*kk2+1][0], s[m][2*kk2+1][1]);
        pi4.w = (int)packbf2(s[m][2*kk2+1][2], s[m][2*kk2+1][3]);
        pa[m] = __builtin_bit_cast(bf16x8, pi4);
      }
#pragma unroll
      for (int df = 0; df < 4; ++df) {
        int row = df * 16 + q15;
        int slot = (kk2 * 4 + g) ^ q15;
        bf16x8 vf = *(const bf16x8*)(&VS[cur][0] + row * 128 + slot * 8);
#pragma unroll
        for (int m = 0; m < 2; ++m)
          o[m][df] = __builtin_amdgcn_mfma_f32_16x16x32_bf16(vf, pa[m], o[m][df], 0, 0, 0);
      }
    }
    WAIT_LGKM;
    BAR;
  }

  int b = bh / 12, h = bh % 12;
#pragma unroll
  for (int m = 0; m < 2; ++m) {
    float inv = 1.0f / l_run[m];
    int row = qrow0 + m * 16;
#pragma unroll
    for (int df = 0; df < 4; ++df) {
      ushort4 ov;
      ov.x = f2bfu(o[m][df][0] * inv);
      ov.y = f2bfu(o[m][df][1] * inv);
      ov.z = f2bfu(o[m][df][2] * inv);
      ov.w = f2bfu(o[m][df][3] * inv);
      *(ushort4*)(comb + (size_t)(b * 4096 + row) * 3840 + h * 64 + df * 16 + g * 4) = ov;
    }
  }
}

extern "C" void kernel_launch(void* const* d_in, const int* in_sizes, int n_in,
                              void* d_out, int out_size, void* d_ws, size_t ws_size,
                              hipStream_t stream) {
  (void)in_sizes; (void)n_in; (void)out_size; (void)ws_size;
  const float* x      = (const float*)d_in[0];
  const float* sin_t  = (const float*)d_in[1];
  const float* cos_t  = (const float*)d_in[2];
  const float* w_norm = (const float*)d_in[3];
  const float* W_in   = (const float*)d_in[4];
  const float* b_in   = (const float*)d_in[5];
  const float* W_out  = (const float*)d_in[6];
  const float* b_out  = (const float*)d_in[7];
  float* out = (float*)d_out;

  const size_t XN_E  = (size_t)8192 * 768;
  ushort* xn      = (ushort*)d_ws;
  ushort* qbuf    = xn + XN_E;
  ushort* kbuf    = qbuf + QKV_E;
  ushort* vt      = kbuf + QKV_E;
  ushort* w_in_t  = vt + QKV_E;
  ushort* w_out_t = w_in_t + (size_t)5376 * 768;
  ushort* comb    = w_out_t + (size_t)768 * 3840;

  prep_k<<<dim3(8960), dim3(256), 0, stream>>>(x, w_norm, xn, W_in, W_out,
                                               w_in_t, w_out_t);
  gemm1_k<<<dim3(2688), dim3(256), 0, stream>>>(xn, w_in_t, b_in, sin_t, cos_t,
                                                qbuf, kbuf, vt, comb);
  attn_k<<<dim3(768), dim3(256), 0, stream>>>(qbuf, kbuf, vt, comb);
  gemm2_k<<<dim3(384), dim3(512), 0, stream>>>(comb, w_out_t, b_out, out);
}